// Round 2
// 1036.400 us; speedup vs baseline: 1.0163x; 1.0163x over previous
//
#include <hip/hip_runtime.h>
#include <hip/hip_bf16.h>
#include <cstdint>
#include <cstddef>

typedef unsigned short u16;
typedef short short8 __attribute__((ext_vector_type(8)));
typedef float floatx4 __attribute__((ext_vector_type(4)));

#define D_DIM 2048
// fallback (128^2) tile params
#define BM 128
#define BN 128
#define BK 32

__device__ __forceinline__ void async_ld16(const u16* g, u16* l) {
  __builtin_amdgcn_global_load_lds(
      (const __attribute__((address_space(1))) void*)g,
      (__attribute__((address_space(3))) void*)l, 16, 0, 0);
}

__device__ __forceinline__ u16 f2bf(float f) {
  __hip_bfloat16 h = __float2bfloat16(f);
  return *reinterpret_cast<u16*>(&h);
}

__device__ __forceinline__ short8 pack8(float4 a, float4 b) {
  short8 p;
  p[0] = (short)f2bf(a.x); p[1] = (short)f2bf(a.y);
  p[2] = (short)f2bf(a.z); p[3] = (short)f2bf(a.w);
  p[4] = (short)f2bf(b.x); p[5] = (short)f2bf(b.y);
  p[6] = (short)f2bf(b.z); p[7] = (short)f2bf(b.w);
  return p;
}

__device__ __forceinline__ float fast_tanh(float x) {
  const float e = __expf(2.f * x);
  return 1.f - 2.f / (e + 1.f);
}
__device__ __forceinline__ float fast_sigmoid(float x) {
  return 1.f / (1.f + __expf(-x));
}

// ---------------- fp32 -> bf16 conversion ----------------
__global__ __launch_bounds__(256) void cvt_f32_bf16(
    const float* __restrict__ src, u16* __restrict__ dst, int n8) {
  int i = blockIdx.x * blockDim.x + threadIdx.x;
  if (i < n8) {
    const float4* s = (const float4*)src + 2 * (size_t)i;
    float4 f0 = s[0], f1 = s[1];
    *((short8*)dst + i) = pack8(f0, f1);
  }
}

// ====================================================================
// 256x256 tile, BK=64, 8-wave (2Mx4N), 8-phase counted-vmcnt pipeline
// (T1+T2+T3/T4+T5 per the m201 template).
//
// LDS (128 KiB): buf[2] x { A[256x64], B[256x64] } bf16, each tile stored
// as 16x2 grid of [16 rows][32 cols] subtiles (1024 B contiguous each),
// st_16x32 swizzle: within a subtile, 16-B quarter index ^= 2 for rows
// 8..15. global_load_lds writes LINEARLY (chunk c -> byte c*16, which IS
// the subtiled layout); the global source address carries the inverse
// swizzle per-lane; ds_read applies the same swizzle on the read side.
//
// Per K-tile: 4 phases, quadrant order (mh,nh) = (0,0),(0,1),(1,1),(1,0).
//   reads:  p0: a(mh0) 8 + b[0] 4   p1: b[1] 4   p2: a(mh1) 8   p3: none
//   stage:  p0: B1(t+1)  p1: A0(t+2)  p2: B0(t+2)  p3: A1(t+2)
//   vmcnt(6) once per tile (end of p3) -> all of tile t+1 resident,
//   3 half-tiles (6 loads) stay in flight across barriers.
// Overwrite safety: each half's overwriting stage is issued >=1 barrier
// after that half's last ds_read phase. No __syncthreads in the loop.
//
// Read-side row-group strides (subtiled layout, u16 units):
//   A: wave covers 64 rows  -> wm*4096, m*1024       (rowgroup = wm*4+m)
//   B: wave covers 32 cols per nh -> wn*2048, n*1024 (rowgroup = nh*8+wn*2+n)
// (R1 bug: B used wn<<12; 3 of 4 N-waves read OOB -> absmax 3.46. Fixed.)
// ====================================================================
template <int NT>
__device__ __forceinline__ void gemm256_8ph(
    const u16* __restrict__ A0, const u16* __restrict__ A1,
    const u16* __restrict__ B0, const u16* __restrict__ B1,
    int mBase, int nBase, u16* lds, floatx4 (&acc)[2][4][2][2])
{
  const int tid  = threadIdx.x;
  const int lane = tid & 63;
  const int quad = lane >> 4;
  const int lrow = lane & 15;
  const int wv   = tid >> 6;
  const int wm   = wv & 1;
  const int wn   = wv >> 1;

  // staging: chunk c0 = tid (load0), c1 = tid+512 (load1, row +64)
  const int lr0   = (tid >> 2) & 15;
  const int rowc0 = ((tid >> 7) << 4) + lr0;   // row within 128-row half
  const int kc0   = (((tid >> 6) & 1) << 5)
                  + (((tid & 3) ^ ((lr0 >> 3) << 1)) << 3);  // inverse-swizzled k
  const size_t aOff = (size_t)(mBase + rowc0) * D_DIM + kc0;
  const size_t bOff = (size_t)(nBase + rowc0) * D_DIM + kc0;
  u16* const dst0 = lds + tid * 8;

  auto stage_half = [&](int j) {
    const int T = j >> 2, slot = j & 3;
    const int h = slot & 1, msel = slot >> 1;     // msel: 0=A, 1=B
    const u16* pA = (T & 32) ? A1 : A0;           // pair switch (NT=64)
    const u16* pB = (T & 32) ? B1 : B0;
    const u16* src = (msel ? (pB + bOff) : (pA + aOff))
                   + (size_t)(h * 128) * D_DIM + ((T & 31) << 6);
    u16* dst = dst0 + ((T & 1) << 15) + (msel << 14) + (h << 13);
    async_ld16(src, dst);
    async_ld16(src + (size_t)64 * D_DIM, dst + 4096);
  };

  // ds_read base: row lrow, k-quarter quad, swizzled within subtile
  const int rdoff = (lrow << 5) + ((quad << 3) ^ ((lrow >> 3) << 4));
  const u16* const rdA = lds + rdoff + (wm << 12);
  const u16* const rdB = lds + 16384 + rdoff + (wn << 11);

  short8 a[4][2];      // current mh's A frags (lifetimes disjoint across mh)
  short8 b[2][2][2];   // [nh][n][ks]

  const int J = 4 * NT;

  // prologue: halves 0..6 (tile0 all + tile1 A0,A1,B0); tile1 B1 comes at p0
#pragma unroll
  for (int j = 0; j < 7; ++j) stage_half(j);
  asm volatile("s_waitcnt vmcnt(6)" ::: "memory");
  __builtin_amdgcn_s_barrier();

#pragma unroll 2
  for (int t = 0; t < NT; ++t) {
    const u16* rA = rdA + ((t & 1) << 15);
    const u16* rB = rdB + ((t & 1) << 15);

    // ---- phase 0: quadrant (mh0, nh0) ----
#pragma unroll
    for (int m = 0; m < 4; ++m)
#pragma unroll
      for (int ks = 0; ks < 2; ++ks)
        a[m][ks] = *(const short8*)(rA + (m << 10) + (ks << 9));
#pragma unroll
    for (int n = 0; n < 2; ++n)
#pragma unroll
      for (int ks = 0; ks < 2; ++ks)
        b[0][n][ks] = *(const short8*)(rB + (n << 10) + (ks << 9));
    if (4 * t + 7 < J) stage_half(4 * t + 7);
    __builtin_amdgcn_s_barrier();
    asm volatile("s_waitcnt lgkmcnt(0)" ::: "memory");
    __builtin_amdgcn_s_setprio(1);
#pragma unroll
    for (int m = 0; m < 4; ++m)
#pragma unroll
      for (int n = 0; n < 2; ++n)
#pragma unroll
        for (int ks = 0; ks < 2; ++ks)
          acc[0][m][0][n] = __builtin_amdgcn_mfma_f32_16x16x32_bf16(
              a[m][ks], b[0][n][ks], acc[0][m][0][n], 0, 0, 0);
    __builtin_amdgcn_s_setprio(0);
    __builtin_amdgcn_s_barrier();

    // ---- phase 1: quadrant (mh0, nh1) ----
#pragma unroll
    for (int n = 0; n < 2; ++n)
#pragma unroll
      for (int ks = 0; ks < 2; ++ks)
        b[1][n][ks] = *(const short8*)(rB + 8192 + (n << 10) + (ks << 9));
    if (4 * t + 8 < J) stage_half(4 * t + 8);
    __builtin_amdgcn_s_barrier();
    asm volatile("s_waitcnt lgkmcnt(0)" ::: "memory");
    __builtin_amdgcn_s_setprio(1);
#pragma unroll
    for (int m = 0; m < 4; ++m)
#pragma unroll
      for (int n = 0; n < 2; ++n)
#pragma unroll
        for (int ks = 0; ks < 2; ++ks)
          acc[0][m][1][n] = __builtin_amdgcn_mfma_f32_16x16x32_bf16(
              a[m][ks], b[1][n][ks], acc[0][m][1][n], 0, 0, 0);
    __builtin_amdgcn_s_setprio(0);
    __builtin_amdgcn_s_barrier();

    // ---- phase 2: quadrant (mh1, nh1) ----
#pragma unroll
    for (int m = 0; m < 4; ++m)
#pragma unroll
      for (int ks = 0; ks < 2; ++ks)
        a[m][ks] = *(const short8*)(rA + 8192 + (m << 10) + (ks << 9));
    if (4 * t + 10 < J) stage_half(4 * t + 10);
    __builtin_amdgcn_s_barrier();
    asm volatile("s_waitcnt lgkmcnt(0)" ::: "memory");
    __builtin_amdgcn_s_setprio(1);
#pragma unroll
    for (int m = 0; m < 4; ++m)
#pragma unroll
      for (int n = 0; n < 2; ++n)
#pragma unroll
        for (int ks = 0; ks < 2; ++ks)
          acc[1][m][1][n] = __builtin_amdgcn_mfma_f32_16x16x32_bf16(
              a[m][ks], b[1][n][ks], acc[1][m][1][n], 0, 0, 0);
    __builtin_amdgcn_s_setprio(0);
    __builtin_amdgcn_s_barrier();

    // ---- phase 3: quadrant (mh1, nh0); counted vmcnt once per tile ----
    if (4 * t + 9 < J) stage_half(4 * t + 9);
    __builtin_amdgcn_s_barrier();
    asm volatile("s_waitcnt lgkmcnt(0)" ::: "memory");
    __builtin_amdgcn_s_setprio(1);
#pragma unroll
    for (int m = 0; m < 4; ++m)
#pragma unroll
      for (int n = 0; n < 2; ++n)
#pragma unroll
        for (int ks = 0; ks < 2; ++ks)
          acc[1][m][0][n] = __builtin_amdgcn_mfma_f32_16x16x32_bf16(
              a[m][ks], b[0][n][ks], acc[1][m][0][n], 0, 0, 0);
    __builtin_amdgcn_s_setprio(0);
    if (t < NT - 2) {
      asm volatile("s_waitcnt vmcnt(6)" ::: "memory");
    } else if (t == NT - 2) {
      asm volatile("s_waitcnt vmcnt(0)" ::: "memory");
    }
    __builtin_amdgcn_s_barrier();
  }
}

// pp = tanh(li*W1^T + x*W2^T + b1 + b2), fused single pipeline (K=4096)
__global__ __launch_bounds__(512, 2) void gemm_pp_8ph(
    const u16* __restrict__ lib, const u16* __restrict__ xb,
    const u16* __restrict__ w1b, const u16* __restrict__ w2b,
    const float* __restrict__ b1, const float* __restrict__ b2,
    u16* __restrict__ pp)
{
  __shared__ __align__(16) u16 lds[65536];  // 128 KiB
  const int bid = blockIdx.x;               // 512 blocks, nwg%8==0
  const int swz = (bid & 7) * 64 + (bid >> 3);   // XCD-contiguous chunks
  const int mBase = (swz >> 3) << 8;
  const int nBase = (swz & 7) << 8;

  floatx4 acc[2][4][2][2];
#pragma unroll
  for (int mh = 0; mh < 2; ++mh)
#pragma unroll
    for (int m = 0; m < 4; ++m)
#pragma unroll
      for (int nh = 0; nh < 2; ++nh)
#pragma unroll
        for (int n = 0; n < 2; ++n)
          acc[mh][m][nh][n] = (floatx4){0.f, 0.f, 0.f, 0.f};

  gemm256_8ph<64>(lib, xb, w1b, w2b, mBase, nBase, lds, acc);

  const int tid  = threadIdx.x;
  const int lane = tid & 63;
  const int quad = lane >> 4;
  const int lrow = lane & 15;
  const int wm   = (tid >> 6) & 1;
  const int wn   = tid >> 7;

  float bsum[2][2];
#pragma unroll
  for (int nh = 0; nh < 2; ++nh)
#pragma unroll
    for (int n = 0; n < 2; ++n) {
      const int col = nBase + nh * 128 + wn * 32 + n * 16 + lrow;
      bsum[nh][n] = b1[col] + b2[col];
    }
#pragma unroll
  for (int mh = 0; mh < 2; ++mh)
#pragma unroll
    for (int m = 0; m < 4; ++m) {
      const int rowb = mBase + mh * 128 + wm * 64 + m * 16 + quad * 4;
#pragma unroll
      for (int nh = 0; nh < 2; ++nh)
#pragma unroll
        for (int n = 0; n < 2; ++n) {
          const int col = nBase + nh * 128 + wn * 32 + n * 16 + lrow;
#pragma unroll
          for (int r = 0; r < 4; ++r) {
            const float v = fast_tanh(acc[mh][m][nh][n][r] + bsum[nh][n]);
            pp[(size_t)(rowb + r) * D_DIM + col] = f2bf(v);
          }
        }
    }
}

// out = sigmoid(pp*V^T + bV) * pe  (K=2048)
__global__ __launch_bounds__(512, 2) void gemm_out_8ph(
    const u16* __restrict__ pp, const u16* __restrict__ vb,
    const float* __restrict__ bV, const float* __restrict__ pe,
    float* __restrict__ out)
{
  __shared__ __align__(16) u16 lds[65536];
  const int bid = blockIdx.x;
  const int swz = (bid & 7) * 64 + (bid >> 3);
  const int mBase = (swz >> 3) << 8;
  const int nBase = (swz & 7) << 8;

  floatx4 acc[2][4][2][2];
#pragma unroll
  for (int mh = 0; mh < 2; ++mh)
#pragma unroll
    for (int m = 0; m < 4; ++m)
#pragma unroll
      for (int nh = 0; nh < 2; ++nh)
#pragma unroll
        for (int n = 0; n < 2; ++n)
          acc[mh][m][nh][n] = (floatx4){0.f, 0.f, 0.f, 0.f};

  gemm256_8ph<32>(pp, pp, vb, vb, mBase, nBase, lds, acc);

  const int tid  = threadIdx.x;
  const int lane = tid & 63;
  const int quad = lane >> 4;
  const int lrow = lane & 15;
  const int wm   = (tid >> 6) & 1;
  const int wn   = tid >> 7;

  float bsv[2][2];
#pragma unroll
  for (int nh = 0; nh < 2; ++nh)
#pragma unroll
    for (int n = 0; n < 2; ++n) {
      const int col = nBase + nh * 128 + wn * 32 + n * 16 + lrow;
      bsv[nh][n] = bV[col];
    }
#pragma unroll
  for (int mh = 0; mh < 2; ++mh)
#pragma unroll
    for (int m = 0; m < 4; ++m) {
      const int rowb = mBase + mh * 128 + wm * 64 + m * 16 + quad * 4;
#pragma unroll
      for (int nh = 0; nh < 2; ++nh)
#pragma unroll
        for (int n = 0; n < 2; ++n) {
          const int col = nBase + nh * 128 + wn * 32 + n * 16 + lrow;
#pragma unroll
          for (int r = 0; r < 4; ++r) {
            const size_t idx = (size_t)(rowb + r) * D_DIM + col;
            out[idx] = fast_sigmoid(acc[mh][m][nh][n][r] + bsv[nh][n]) * pe[idx];
          }
        }
    }
}

// ---------------- fallback path (small ws): fp32-A 128^2 kernel -----------
__device__ __forceinline__ void phase_f32A(
    const float* __restrict__ A, const u16* __restrict__ Bw,
    int mBase, int nBase, u16* As, u16* Bs, floatx4 acc[4][4])
{
  const int tid  = threadIdx.x;
  const int lane = tid & 63;
  const int quad = lane >> 4;
  const int lrow = lane & 15;
  const int wv   = tid >> 6;
  const int wm   = wv & 1;
  const int wn   = wv >> 1;

  const int r0 = tid >> 2;
  const int c0 = (tid & 3) * 8;
  const u16* gB = Bw + (size_t)(nBase + r0) * D_DIM + c0;
  u16* lB0 = Bs + tid * 8;
  u16* lB1 = Bs + (tid + 256) * 8;

  const int ar = tid >> 1;
  const int ac = (tid & 1) * 16;
  const float* gA = A + (size_t)(mBase + ar) * D_DIM + ac;
  u16* wA = As + ar * BK + ac;

  for (int kt = 0; kt < D_DIM / BK; ++kt) {
    const int k0 = kt * BK;
    __syncthreads();
    async_ld16(gB + k0, lB0);
    async_ld16(gB + (size_t)64 * D_DIM + k0, lB1);
    float4 f0 = *(const float4*)(gA + k0);
    float4 f1 = *(const float4*)(gA + k0 + 4);
    float4 f2 = *(const float4*)(gA + k0 + 8);
    float4 f3 = *(const float4*)(gA + k0 + 12);
    *(short8*)(wA)     = pack8(f0, f1);
    *(short8*)(wA + 8) = pack8(f2, f3);
    __syncthreads();

    short8 a[4], b[4];
#pragma unroll
    for (int i = 0; i < 4; ++i) {
      const int row = wm * 64 + i * 16 + lrow;
      a[i] = *(const short8*)(As + row * BK + quad * 8);
      const int col = wn * 64 + i * 16 + lrow;
      b[i] = *(const short8*)(Bs + col * BK + quad * 8);
    }
#pragma unroll
    for (int i = 0; i < 4; ++i)
#pragma unroll
      for (int j = 0; j < 4; ++j)
        acc[i][j] = __builtin_amdgcn_mfma_f32_16x16x32_bf16(a[i], b[j], acc[i][j], 0, 0, 0);
  }
}

__global__ __launch_bounds__(256) void gemm_pp_f32(
    const float* __restrict__ li, const float* __restrict__ x,
    const u16* __restrict__ w1b, const u16* __restrict__ w2b,
    const float* __restrict__ b1, const float* __restrict__ b2,
    u16* __restrict__ pp)
{
  __shared__ __align__(16) u16 As[BM * BK];
  __shared__ __align__(16) u16 Bs[BN * BK];

  floatx4 acc[4][4];
#pragma unroll
  for (int i = 0; i < 4; ++i)
#pragma unroll
    for (int j = 0; j < 4; ++j)
      acc[i][j] = (floatx4){0.f, 0.f, 0.f, 0.f};

  const int nBase = blockIdx.x * BN;
  const int mBase = blockIdx.y * BM;

  phase_f32A(li, w1b, mBase, nBase, As, Bs, acc);
  phase_f32A(x,  w2b, mBase, nBase, As, Bs, acc);

  const int tid  = threadIdx.x;
  const int lane = tid & 63;
  const int quad = lane >> 4;
  const int lrow = lane & 15;
  const int wv   = tid >> 6;
  const int wm   = wv & 1;
  const int wn   = wv >> 1;

#pragma unroll
  for (int j = 0; j < 4; ++j) {
    const int col = nBase + wn * 64 + j * 16 + lrow;
    const float bs = b1[col] + b2[col];
#pragma unroll
    for (int i = 0; i < 4; ++i) {
      const int rowb = mBase + wm * 64 + i * 16 + quad * 4;
#pragma unroll
      for (int r = 0; r < 4; ++r) {
        const float v = fast_tanh(acc[i][j][r] + bs);
        pp[(size_t)(rowb + r) * D_DIM + col] = f2bf(v);
      }
    }
  }
}

extern "C" void kernel_launch(void* const* d_in, const int* in_sizes, int n_in,
                              void* d_out, int out_size, void* d_ws, size_t ws_size,
                              hipStream_t stream) {
  const float* x  = (const float*)d_in[0];
  const float* li = (const float*)d_in[1];
  const float* pe = (const float*)d_in[2];
  const float* W1 = (const float*)d_in[5];
  const float* b1 = (const float*)d_in[6];
  const float* W2 = (const float*)d_in[7];
  const float* b2 = (const float*)d_in[8];
  const float* V  = (const float*)d_in[9];
  const float* bV = (const float*)d_in[10];
  float* out = (float*)d_out;

  const int M = 2048 * 8;                      // S*B = 16384
  const size_t nW  = (size_t)D_DIM * D_DIM;    // 4.19M
  const size_t nA  = (size_t)M * D_DIM;        // 33.5M

  // ws layout (u16 elems): w1b | w2b | vb | pp | lib | xb
  u16* w1b = (u16*)d_ws;
  u16* w2b = w1b + nW;
  u16* vb  = w2b + nW;
  u16* pp  = vb  + nW;
  u16* lib = pp  + nA;
  u16* xb  = lib + nA;
  const size_t need_full = (3 * nW + 3 * nA) * sizeof(u16);  // ~226 MB

  const int nW8 = (int)(nW / 8);
  const int nA8 = (int)(nA / 8);

  cvt_f32_bf16<<<nW8 / 256, 256, 0, stream>>>(W1, w1b, nW8);
  cvt_f32_bf16<<<nW8 / 256, 256, 0, stream>>>(W2, w2b, nW8);
  cvt_f32_bf16<<<nW8 / 256, 256, 0, stream>>>(V,  vb,  nW8);

  if (ws_size >= need_full) {
    cvt_f32_bf16<<<nA8 / 256, 256, 0, stream>>>(li, lib, nA8);
    cvt_f32_bf16<<<nA8 / 256, 256, 0, stream>>>(x,  xb,  nA8);
    gemm_pp_8ph<<<dim3(512), dim3(512), 0, stream>>>(lib, xb, w1b, w2b, b1, b2, pp);
  } else {
    dim3 grid(D_DIM / BN, M / BM);  // (16, 128)
    gemm_pp_f32<<<grid, dim3(256), 0, stream>>>(li, x, w1b, w2b, b1, b2, pp);
  }
  gemm_out_8ph<<<dim3(512), dim3(512), 0, stream>>>(pp, vb, bV, pe, out);
}